// Round 7
// baseline (787.401 us; speedup 1.0000x reference)
//
#include <hip/hip_runtime.h>
#include <hip/hip_bf16.h>

// GCN sparse aggregation: out[rows[e], :] += vals[e] * embeds[cols[e], :]
// E = 1.6M, N = 100K, D = 64, fp32.
//
// Round 18: delete K2's row-sort; accumulate into LDS acc[128][64] via
// ds_add_f32 (fire-and-forget, conflict-free at acc[row][lane]).
//  - The row-sort (hist atomic + 128-scan + scatter atomic + scattered
//    LDS writes, 2 barriers, 495K bank-conflict cycles) existed only to
//    keep the accumulator in registers. Round-12 proved LDS f32 atomics
//    are fine -- its 690us failure was uniform per-edge GLOBAL loads,
//    which our coalesced flat load + LDS broadcast already avoids.
//  - Flat load now writes ebuf LINEARLY (no register hold). Each wave
//    streams a contiguous slice with a constant 8-deep gather pipeline:
//    no drain at row boundaries (rows avg ~16 edges).
//  - Per edge: bcast ds_read + 128B gather + ds_add_f32. Epilogue:
//    coalesced acc -> out flush.
//  LDS ~64.5KB -> 2 blocks/CU (16 waves, ~= current effective 15).
//  K1 (round-17: transposed offg) unchanged for attribution.

#define D_FEAT 64
#define LOG_RPB 7
#define ROWS_PER_BUCKET 128
#define N_BUCKETS 782          // ceil(100000 / 128); guarded at runtime
#define PB 256                 // partition chunks / blocks
#define K1_THREADS 1024
#define K1_CAP 6272            // LDS chunk buffer (chunk = 6250 for E=1.6M)
#define EPT 7                  // edges per thread in partition (6250/1024)
#define K4_CAP 3072            // agg LDS buffer (bucket mean 2046, +22 sigma)
#define EPT2 6                 // K4_CAP / 512

typedef unsigned long long u64;

__device__ inline unsigned bf16rne(float x) {
    unsigned u = __float_as_uint(x);
    return (u + 0x7FFFu + ((u >> 16) & 1u)) >> 16;
}

__device__ inline int wave_incl_scan(int x, int lane) {
    #pragma unroll
    for (int o = 1; o < 64; o <<= 1) {
        int y = __shfl_up(x, o, 64);
        if (lane >= o) x += y;
    }
    return x;
}

// ---------------- fallback (round-1 atomic path) ----------------
__global__ __launch_bounds__(256) void gcn_scatter_fallback(
    const int* __restrict__ rows, const int* __restrict__ cols,
    const float* __restrict__ vals, const float* __restrict__ embeds,
    float* __restrict__ out, int n_edges)
{
    int gtid = blockIdx.x * blockDim.x + threadIdx.x;
    int e = gtid >> 4;
    if (e >= n_edges) return;
    int lane4 = gtid & 15;
    int row = rows[e]; int col = cols[e]; float v = vals[e];
    const float4* ep = reinterpret_cast<const float4*>(embeds + (size_t)col * D_FEAT);
    float4 m = ep[lane4];
    float* op = out + (size_t)row * D_FEAT + lane4 * 4;
    atomicAdd(op + 0, v * m.x);
    atomicAdd(op + 1, v * m.y);
    atomicAdd(op + 2, v * m.z);
    atomicAdd(op + 3, v * m.w);
}

// ---------------- K1: per-chunk counting sort + coalesced dump + convert ----------------
// 256 blocks x 1024 thr; 56.5KB LDS.
__global__ __launch_bounds__(1024, 4) void k_partition_conv(
    const int* __restrict__ rows, const int* __restrict__ cols,
    const float* __restrict__ vals, u64* __restrict__ sorted,
    int* __restrict__ offg, const float* __restrict__ embeds,
    unsigned short* __restrict__ emb16, int do_conv,
    int n_edges, int n_elems, int chunk)
{
    __shared__ u64 ebuf[K1_CAP];          // 50,176 B
    __shared__ int lh[N_BUCKETS];         //  3,128 B
    __shared__ int cur[N_BUCKETS];        //  3,128 B
    __shared__ int segtot[16];

    int blk = blockIdx.x, tid = threadIdx.x;
    int lane = tid & 63, wid = tid >> 6;     // 16 waves
    int beg = blk * chunk;
    int end = min(beg + chunk, n_edges);
    int cnt = end - beg;

    for (int i = tid; i < N_BUCKETS; i += K1_THREADS) lh[i] = 0;
    __syncthreads();

    // load edges into registers + bucket histogram (LDS int atomics)
    u64 ent[EPT]; int eb[EPT]; bool okk[EPT];
    #pragma unroll
    for (int k = 0; k < EPT; ++k) {
        int e = beg + k * K1_THREADS + tid;
        okk[k] = (e < end);
        if (okk[k]) {
            int r = rows[e];
            eb[k] = r >> LOG_RPB;
            unsigned meta = (unsigned)cols[e] |
                            ((unsigned)(r & (ROWS_PER_BUCKET - 1)) << 17);
            ent[k] = ((u64)__float_as_uint(vals[e]) << 32) | meta;
            atomicAdd(&lh[eb[k]], 1);
        }
    }
    __syncthreads();

    // in-LDS scan of 782 counters (13 wave-segments over 16 waves)
    for (int seg = wid; seg * 64 < N_BUCKETS; seg += 16) {
        int idx = seg * 64 + lane;
        int v = (idx < N_BUCKETS) ? lh[idx] : 0;
        int inc = wave_incl_scan(v, lane);
        if (idx < N_BUCKETS) lh[idx] = inc - v;
        if (lane == 63) segtot[seg] = inc;
    }
    __syncthreads();
    if (tid < 64) {
        int v = (tid < 13) ? segtot[tid] : 0;
        int inc = wave_incl_scan(v, tid);
        if (tid < 13) segtot[tid] = inc - v;
    }
    __syncthreads();
    // offsets: TRANSPOSED global table offg[bucket][chunk] (L2-resident)
    for (int i = tid; i < N_BUCKETS; i += K1_THREADS) {
        int excl = lh[i] + segtot[i >> 6];
        offg[(size_t)i * PB + blk] = excl;
        cur[i] = excl;
    }
    if (tid == 0) offg[(size_t)N_BUCKETS * PB + blk] = cnt;
    __syncthreads();

    // scatter from REGISTERS into LDS bucket-sorted
    #pragma unroll
    for (int k = 0; k < EPT; ++k) {
        if (okk[k]) {
            int p = atomicAdd(&cur[eb[k]], 1);   // LDS int atomic only
            ebuf[p] = ent[k];
        }
    }
    __syncthreads();

    // dump: fully coalesced linear copy
    for (int i = tid; i < cnt; i += K1_THREADS)
        sorted[beg + i] = ebuf[i];

    // convert slice fp32 -> bf16 (packed, independent; overlaps tail)
    if (do_conv) {
        const float4* src4 = (const float4*)embeds;
        u64* dst4 = (u64*)emb16;
        int nq = n_elems >> 2;
        for (int i = blk * K1_THREADS + tid; i < nq; i += PB * K1_THREADS) {
            float4 f = src4[i];
            u64 pk = (u64)bf16rne(f.x) | ((u64)bf16rne(f.y) << 16) |
                     ((u64)bf16rne(f.z) << 32) | ((u64)bf16rne(f.w) << 48);
            dst4[i] = pk;
        }
        if (blk == 0 && tid < (n_elems & 3)) {
            int i = (nq << 2) + tid;
            emb16[i] = (unsigned short)bf16rne(embeds[i]);
        }
    }
}

// ---------------- K2: flat load -> LDS ebuf, stream + ds_add_f32 into acc ----------------
template <bool USE16>
__global__ __launch_bounds__(512) void k_aggregate_atomic(
    const u64* __restrict__ sorted, const int* __restrict__ offg,
    const float* __restrict__ embeds, const unsigned short* __restrict__ emb16,
    float* __restrict__ out, int n_nodes, int chunk)
{
    __shared__ float acc[ROWS_PER_BUCKET * D_FEAT];   // 32 KB
    __shared__ u64 ebuf[K4_CAP];                      // 24 KB
    __shared__ int sOff[PB], sLen[PB];                //  2 KB
    __shared__ int pre[PB + 1];                       //  1 KB
    __shared__ int base[PB];                          //  1 KB
    __shared__ unsigned char segid[K4_CAP];           //  3 KB
    __shared__ int wtot[4], wpre[4];

    int b = blockIdx.x, tid = threadIdx.x;
    int lane = tid & 63, wid = tid >> 6;   // 8 waves
    int rowbase = b * ROWS_PER_BUCKET;
    int nrows = n_nodes - rowbase;
    if (nrows > ROWS_PER_BUCKET) nrows = ROWS_PER_BUCKET;

    // ---- segment descriptors: two CONTIGUOUS 1KB runs (transposed table) ----
    if (tid < PB) {
        int o0 = offg[(size_t)b * PB + tid];
        int o1 = offg[(size_t)(b + 1) * PB + tid];
        sOff[tid] = o0;
        sLen[tid] = o1 - o0;
    }
    // zero the LDS accumulator (overlaps descriptor fetch)
    for (int i = tid; i < ROWS_PER_BUCKET * D_FEAT; i += 512) acc[i] = 0.0f;
    __syncthreads();

    // ---- exclusive prefix of sLen -> pre[0..PB], n = pre[PB] ----
    if (wid < 4) {
        int v = sLen[wid * 64 + lane];
        int inc = wave_incl_scan(v, lane);
        pre[wid * 64 + lane] = inc - v;
        if (lane == 63) wtot[wid] = inc;
    }
    __syncthreads();
    if (tid == 0) {
        int a = 0;
        #pragma unroll
        for (int j = 0; j < 4; ++j) { wpre[j] = a; a += wtot[j]; }
        pre[PB] = a;
    }
    __syncthreads();
    if (tid < PB) pre[tid] += wpre[tid >> 6];
    __syncthreads();
    int n = pre[PB];

    if (n <= K4_CAP) {
        // ---- segid/base lookup (flat idx -> segment) ----
        if (tid < PB) {
            int p0 = pre[tid];
            int p1 = pre[tid + 1];
            base[tid] = tid * chunk + sOff[tid] - p0;
            for (int j = p0; j < p1; ++j) segid[j] = (unsigned char)tid;
        }
        __syncthreads();

        // ---- flat coalesced load straight into ebuf (linear LDS writes) ----
        #pragma unroll
        for (int k = 0; k < EPT2; ++k) {
            int i = tid + k * 512;
            if (i < n) {
                int s = segid[i];
                ebuf[i] = sorted[(size_t)(base[s] + i)];
            }
        }
        __syncthreads();

        #define GATHER(t) (USE16 \
            ? __uint_as_float((unsigned)emb16[(size_t)((t) & 0x1FFFF) * D_FEAT + lane] << 16) \
            : embeds[(size_t)((t) & 0x1FFFF) * D_FEAT + lane])
        #define ACCUM(t, m) \
            atomicAdd(&acc[(int)(((t) >> 17) & (ROWS_PER_BUCKET - 1)) * D_FEAT + lane], \
                      __uint_as_float((unsigned)((t) >> 32)) * (m))

        // ---- stream: wave w owns contiguous slice [w*n/8, (w+1)*n/8) ----
        // constant 8-deep gather pipeline; ds_add_f32 is fire-and-forget.
        int e0 = (wid * n) >> 3;
        int e1 = ((wid + 1) * n) >> 3;
        int j = e0;
        for (; j + 7 < e1; j += 8) {
            u64 t0 = ebuf[j + 0], t1 = ebuf[j + 1], t2 = ebuf[j + 2], t3 = ebuf[j + 3];
            u64 t4 = ebuf[j + 4], t5 = ebuf[j + 5], t6 = ebuf[j + 6], t7 = ebuf[j + 7];
            float m0 = GATHER(t0), m1 = GATHER(t1), m2 = GATHER(t2), m3 = GATHER(t3);
            float m4 = GATHER(t4), m5 = GATHER(t5), m6 = GATHER(t6), m7 = GATHER(t7);
            ACCUM(t0, m0); ACCUM(t1, m1); ACCUM(t2, m2); ACCUM(t3, m3);
            ACCUM(t4, m4); ACCUM(t5, m5); ACCUM(t6, m6); ACCUM(t7, m7);
        }
        for (; j + 3 < e1; j += 4) {
            u64 t0 = ebuf[j + 0], t1 = ebuf[j + 1], t2 = ebuf[j + 2], t3 = ebuf[j + 3];
            float m0 = GATHER(t0), m1 = GATHER(t1), m2 = GATHER(t2), m3 = GATHER(t3);
            ACCUM(t0, m0); ACCUM(t1, m1); ACCUM(t2, m2); ACCUM(t3, m3);
        }
        for (; j < e1; ++j) {
            u64 t0 = ebuf[j];
            float m0 = GATHER(t0);
            ACCUM(t0, m0);
        }
        #undef ACCUM
        __syncthreads();

        // ---- coalesced flush acc -> out ----
        int lim = nrows * D_FEAT;
        for (int i = tid; i < lim; i += 512)
            out[(size_t)rowbase * D_FEAT + i] = acc[i];
        #undef GATHER
    } else {
        // ---- oversized-bucket fallback (statistically never; correct) ----
        #define GATHER(t) (USE16 \
            ? __uint_as_float((unsigned)emb16[(size_t)((t) & 0x1FFFF) * D_FEAT + lane] << 16) \
            : embeds[(size_t)((t) & 0x1FFFF) * D_FEAT + lane])
        for (int i = tid; i < nrows * D_FEAT; i += 512)
            out[(size_t)rowbase * D_FEAT + i] = 0.0f;
        __syncthreads();
        for (int seg = wid; seg < PB; seg += 8) {
            int len = sLen[seg];
            const u64* sp = sorted + (size_t)seg * chunk + sOff[seg];
            for (int i = 0; i < len; ++i) {
                u64 ent = sp[i];
                int lr = (int)((ent >> 17) & (ROWS_PER_BUCKET - 1));
                float v = __uint_as_float((unsigned)(ent >> 32));
                float m = GATHER(ent);
                atomicAdd(&out[(size_t)(rowbase + lr) * D_FEAT + lane], v * m);
            }
        }
        #undef GATHER
    }
}

extern "C" void kernel_launch(void* const* d_in, const int* in_sizes, int n_in,
                              void* d_out, int out_size, void* d_ws, size_t ws_size,
                              hipStream_t stream) {
    const int*   rows   = (const int*)d_in[0];
    const int*   cols   = (const int*)d_in[1];
    const float* vals   = (const float*)d_in[2];
    const float* embeds = (const float*)d_in[3];

    float* out = (float*)d_out;
    int n_edges = in_sizes[0];
    int n_nodes = out_size / D_FEAT;
    int n_buckets = (n_nodes + ROWS_PER_BUCKET - 1) >> LOG_RPB;
    int chunk = (n_edges + PB - 1) / PB;
    int n_elems = n_nodes * D_FEAT;

    // ws layout: [sorted: E u64][offg: (B+1)*PB ints][emb16: n_elems u16]
    size_t base_need = (size_t)n_edges * sizeof(u64) +
                       (size_t)(N_BUCKETS + 1) * PB * sizeof(int) + 256;
    size_t full_need = base_need + (size_t)n_elems * sizeof(unsigned short) + 256;

    if (n_buckets != N_BUCKETS || chunk > K1_CAP || chunk > EPT * K1_THREADS ||
        ws_size < base_need) {
        hipMemsetAsync(out, 0, (size_t)out_size * sizeof(float), stream);
        long long total_threads = (long long)n_edges * 16;
        int block = 256;
        int grid = (int)((total_threads + block - 1) / block);
        gcn_scatter_fallback<<<grid, block, 0, stream>>>(rows, cols, vals, embeds, out, n_edges);
        return;
    }

    u64* sorted = (u64*)d_ws;
    int* offg   = (int*)(sorted + n_edges);                  // [B+1][PB] transposed
    unsigned short* emb16 = (unsigned short*)
        (((uintptr_t)(offg + (size_t)(N_BUCKETS + 1) * PB) + 15) & ~(uintptr_t)15);

    bool use16 = (ws_size >= full_need);

    k_partition_conv<<<PB, K1_THREADS, 0, stream>>>(rows, cols, vals, sorted, offg,
                                                    embeds, emb16, use16 ? 1 : 0,
                                                    n_edges, n_elems, chunk);
    if (use16)
        k_aggregate_atomic<true><<<N_BUCKETS, 512, 0, stream>>>(
            sorted, offg, embeds, emb16, out, n_nodes, chunk);
    else
        k_aggregate_atomic<false><<<N_BUCKETS, 512, 0, stream>>>(
            sorted, offg, embeds, emb16, out, n_nodes, chunk);
}

// Round 8
// 157.722 us; speedup vs baseline: 4.9923x; 4.9923x over previous
//
#include <hip/hip_runtime.h>
#include <hip/hip_bf16.h>

// GCN sparse aggregation: out[rows[e], :] += vals[e] * embeds[cols[e], :]
// E = 1.6M, N = 100K, D = 64, fp32.
//
// Round 19: round-18's structure, INTEGER LDS accumulator.
//  - Rounds 12/18 both hit ~700us with atomicAdd on __shared__ FLOAT:
//    hipcc (no -munsafe-fp-atomics) lowers it to a CAS retry loop
//    (VGPR 52 / SGPR 112 bloat, VALUBusy 3%). LDS INT atomicAdd is
//    native ds_add_u32 -- K1 does 3.2M of them in a ~44us kernel.
//  - So: acc[128][64] is int, fixed-point Q8.23. Per edge:
//    ip = round((v*2^23) * m); ds_add_u32 acc[row*64+lane].
//    Fire-and-forget, conflict-free across lanes, two's-complement
//    wraparound-safe (row sums ~16 terms, |sum| << 2^8 headroom;
//    rounding ~1e-6 vs existing bf16 absmax 0.0625).
//  - Keeps round-18's wins: no hist, no 128-scan, no row-scatter,
//    2 fewer barriers, linear ebuf writes, constant 8-deep gather
//    pipeline with no drain at row boundaries.
//  K1 (round-17: transposed offg) unchanged for attribution.

#define D_FEAT 64
#define LOG_RPB 7
#define ROWS_PER_BUCKET 128
#define N_BUCKETS 782          // ceil(100000 / 128); guarded at runtime
#define PB 256                 // partition chunks / blocks
#define K1_THREADS 1024
#define K1_CAP 6272            // LDS chunk buffer (chunk = 6250 for E=1.6M)
#define EPT 7                  // edges per thread in partition (6250/1024)
#define K4_CAP 3072            // agg LDS buffer (bucket mean 2046, +22 sigma)
#define EPT2 6                 // K4_CAP / 512
#define FIXSCALE 8388608.0f    // 2^23 (Q8.23)
#define FIXINV   (1.0f / 8388608.0f)

typedef unsigned long long u64;

__device__ inline unsigned bf16rne(float x) {
    unsigned u = __float_as_uint(x);
    return (u + 0x7FFFu + ((u >> 16) & 1u)) >> 16;
}

__device__ inline int wave_incl_scan(int x, int lane) {
    #pragma unroll
    for (int o = 1; o < 64; o <<= 1) {
        int y = __shfl_up(x, o, 64);
        if (lane >= o) x += y;
    }
    return x;
}

// ---------------- fallback (round-1 atomic path) ----------------
__global__ __launch_bounds__(256) void gcn_scatter_fallback(
    const int* __restrict__ rows, const int* __restrict__ cols,
    const float* __restrict__ vals, const float* __restrict__ embeds,
    float* __restrict__ out, int n_edges)
{
    int gtid = blockIdx.x * blockDim.x + threadIdx.x;
    int e = gtid >> 4;
    if (e >= n_edges) return;
    int lane4 = gtid & 15;
    int row = rows[e]; int col = cols[e]; float v = vals[e];
    const float4* ep = reinterpret_cast<const float4*>(embeds + (size_t)col * D_FEAT);
    float4 m = ep[lane4];
    float* op = out + (size_t)row * D_FEAT + lane4 * 4;
    atomicAdd(op + 0, v * m.x);
    atomicAdd(op + 1, v * m.y);
    atomicAdd(op + 2, v * m.z);
    atomicAdd(op + 3, v * m.w);
}

// ---------------- K1: per-chunk counting sort + coalesced dump + convert ----------------
// 256 blocks x 1024 thr; 56.5KB LDS.
__global__ __launch_bounds__(1024, 4) void k_partition_conv(
    const int* __restrict__ rows, const int* __restrict__ cols,
    const float* __restrict__ vals, u64* __restrict__ sorted,
    int* __restrict__ offg, const float* __restrict__ embeds,
    unsigned short* __restrict__ emb16, int do_conv,
    int n_edges, int n_elems, int chunk)
{
    __shared__ u64 ebuf[K1_CAP];          // 50,176 B
    __shared__ int lh[N_BUCKETS];         //  3,128 B
    __shared__ int cur[N_BUCKETS];        //  3,128 B
    __shared__ int segtot[16];

    int blk = blockIdx.x, tid = threadIdx.x;
    int lane = tid & 63, wid = tid >> 6;     // 16 waves
    int beg = blk * chunk;
    int end = min(beg + chunk, n_edges);
    int cnt = end - beg;

    for (int i = tid; i < N_BUCKETS; i += K1_THREADS) lh[i] = 0;
    __syncthreads();

    // load edges into registers + bucket histogram (LDS int atomics)
    u64 ent[EPT]; int eb[EPT]; bool okk[EPT];
    #pragma unroll
    for (int k = 0; k < EPT; ++k) {
        int e = beg + k * K1_THREADS + tid;
        okk[k] = (e < end);
        if (okk[k]) {
            int r = rows[e];
            eb[k] = r >> LOG_RPB;
            unsigned meta = (unsigned)cols[e] |
                            ((unsigned)(r & (ROWS_PER_BUCKET - 1)) << 17);
            ent[k] = ((u64)__float_as_uint(vals[e]) << 32) | meta;
            atomicAdd(&lh[eb[k]], 1);
        }
    }
    __syncthreads();

    // in-LDS scan of 782 counters (13 wave-segments over 16 waves)
    for (int seg = wid; seg * 64 < N_BUCKETS; seg += 16) {
        int idx = seg * 64 + lane;
        int v = (idx < N_BUCKETS) ? lh[idx] : 0;
        int inc = wave_incl_scan(v, lane);
        if (idx < N_BUCKETS) lh[idx] = inc - v;
        if (lane == 63) segtot[seg] = inc;
    }
    __syncthreads();
    if (tid < 64) {
        int v = (tid < 13) ? segtot[tid] : 0;
        int inc = wave_incl_scan(v, tid);
        if (tid < 13) segtot[tid] = inc - v;
    }
    __syncthreads();
    // offsets: TRANSPOSED global table offg[bucket][chunk] (L2-resident)
    for (int i = tid; i < N_BUCKETS; i += K1_THREADS) {
        int excl = lh[i] + segtot[i >> 6];
        offg[(size_t)i * PB + blk] = excl;
        cur[i] = excl;
    }
    if (tid == 0) offg[(size_t)N_BUCKETS * PB + blk] = cnt;
    __syncthreads();

    // scatter from REGISTERS into LDS bucket-sorted
    #pragma unroll
    for (int k = 0; k < EPT; ++k) {
        if (okk[k]) {
            int p = atomicAdd(&cur[eb[k]], 1);   // LDS int atomic only
            ebuf[p] = ent[k];
        }
    }
    __syncthreads();

    // dump: fully coalesced linear copy
    for (int i = tid; i < cnt; i += K1_THREADS)
        sorted[beg + i] = ebuf[i];

    // convert slice fp32 -> bf16 (packed, independent; overlaps tail)
    if (do_conv) {
        const float4* src4 = (const float4*)embeds;
        u64* dst4 = (u64*)emb16;
        int nq = n_elems >> 2;
        for (int i = blk * K1_THREADS + tid; i < nq; i += PB * K1_THREADS) {
            float4 f = src4[i];
            u64 pk = (u64)bf16rne(f.x) | ((u64)bf16rne(f.y) << 16) |
                     ((u64)bf16rne(f.z) << 32) | ((u64)bf16rne(f.w) << 48);
            dst4[i] = pk;
        }
        if (blk == 0 && tid < (n_elems & 3)) {
            int i = (nq << 2) + tid;
            emb16[i] = (unsigned short)bf16rne(embeds[i]);
        }
    }
}

// ---------------- K2: flat load -> LDS ebuf, stream + ds_add_u32 (Q8.23) into acc ----------------
template <bool USE16>
__global__ __launch_bounds__(512) void k_aggregate_iatomic(
    const u64* __restrict__ sorted, const int* __restrict__ offg,
    const float* __restrict__ embeds, const unsigned short* __restrict__ emb16,
    float* __restrict__ out, int n_nodes, int chunk)
{
    __shared__ int acc[ROWS_PER_BUCKET * D_FEAT];     // 32 KB (Q8.23 fixed)
    __shared__ u64 ebuf[K4_CAP];                      // 24 KB
    __shared__ int sOff[PB], sLen[PB];                //  2 KB
    __shared__ int pre[PB + 1];                       //  1 KB
    __shared__ int base[PB];                          //  1 KB
    __shared__ unsigned char segid[K4_CAP];           //  3 KB
    __shared__ int wtot[4], wpre[4];

    int b = blockIdx.x, tid = threadIdx.x;
    int lane = tid & 63, wid = tid >> 6;   // 8 waves
    int rowbase = b * ROWS_PER_BUCKET;
    int nrows = n_nodes - rowbase;
    if (nrows > ROWS_PER_BUCKET) nrows = ROWS_PER_BUCKET;

    // ---- segment descriptors: two CONTIGUOUS 1KB runs (transposed table) ----
    if (tid < PB) {
        int o0 = offg[(size_t)b * PB + tid];
        int o1 = offg[(size_t)(b + 1) * PB + tid];
        sOff[tid] = o0;
        sLen[tid] = o1 - o0;
    }
    // zero the LDS accumulator (overlaps descriptor fetch)
    for (int i = tid; i < ROWS_PER_BUCKET * D_FEAT; i += 512) acc[i] = 0;
    __syncthreads();

    // ---- exclusive prefix of sLen -> pre[0..PB], n = pre[PB] ----
    if (wid < 4) {
        int v = sLen[wid * 64 + lane];
        int inc = wave_incl_scan(v, lane);
        pre[wid * 64 + lane] = inc - v;
        if (lane == 63) wtot[wid] = inc;
    }
    __syncthreads();
    if (tid == 0) {
        int a = 0;
        #pragma unroll
        for (int j = 0; j < 4; ++j) { wpre[j] = a; a += wtot[j]; }
        pre[PB] = a;
    }
    __syncthreads();
    if (tid < PB) pre[tid] += wpre[tid >> 6];
    __syncthreads();
    int n = pre[PB];

    if (n <= K4_CAP) {
        // ---- segid/base lookup (flat idx -> segment) ----
        if (tid < PB) {
            int p0 = pre[tid];
            int p1 = pre[tid + 1];
            base[tid] = tid * chunk + sOff[tid] - p0;
            for (int j = p0; j < p1; ++j) segid[j] = (unsigned char)tid;
        }
        __syncthreads();

        // ---- flat coalesced load straight into ebuf (linear LDS writes) ----
        #pragma unroll
        for (int k = 0; k < EPT2; ++k) {
            int i = tid + k * 512;
            if (i < n) {
                int s = segid[i];
                ebuf[i] = sorted[(size_t)(base[s] + i)];
            }
        }
        __syncthreads();

        #define GATHER(t) (USE16 \
            ? __uint_as_float((unsigned)emb16[(size_t)((t) & 0x1FFFF) * D_FEAT + lane] << 16) \
            : embeds[(size_t)((t) & 0x1FFFF) * D_FEAT + lane])
        // v pre-scaled by 2^23; native ds_add_u32, fire-and-forget
        #define ACCUM(t, m) \
            atomicAdd(&acc[(int)(((t) >> 17) & (ROWS_PER_BUCKET - 1)) * D_FEAT + lane], \
                      __float2int_rn(__uint_as_float((unsigned)((t) >> 32)) * FIXSCALE * (m)))

        // ---- stream: wave w owns contiguous slice [w*n/8, (w+1)*n/8) ----
        int e0 = (wid * n) >> 3;
        int e1 = ((wid + 1) * n) >> 3;
        int j = e0;
        for (; j + 7 < e1; j += 8) {
            u64 t0 = ebuf[j + 0], t1 = ebuf[j + 1], t2 = ebuf[j + 2], t3 = ebuf[j + 3];
            u64 t4 = ebuf[j + 4], t5 = ebuf[j + 5], t6 = ebuf[j + 6], t7 = ebuf[j + 7];
            float m0 = GATHER(t0), m1 = GATHER(t1), m2 = GATHER(t2), m3 = GATHER(t3);
            float m4 = GATHER(t4), m5 = GATHER(t5), m6 = GATHER(t6), m7 = GATHER(t7);
            ACCUM(t0, m0); ACCUM(t1, m1); ACCUM(t2, m2); ACCUM(t3, m3);
            ACCUM(t4, m4); ACCUM(t5, m5); ACCUM(t6, m6); ACCUM(t7, m7);
        }
        for (; j + 3 < e1; j += 4) {
            u64 t0 = ebuf[j + 0], t1 = ebuf[j + 1], t2 = ebuf[j + 2], t3 = ebuf[j + 3];
            float m0 = GATHER(t0), m1 = GATHER(t1), m2 = GATHER(t2), m3 = GATHER(t3);
            ACCUM(t0, m0); ACCUM(t1, m1); ACCUM(t2, m2); ACCUM(t3, m3);
        }
        for (; j < e1; ++j) {
            u64 t0 = ebuf[j];
            float m0 = GATHER(t0);
            ACCUM(t0, m0);
        }
        #undef ACCUM
        __syncthreads();

        // ---- coalesced flush: Q8.23 -> float ----
        int lim = nrows * D_FEAT;
        for (int i = tid; i < lim; i += 512)
            out[(size_t)rowbase * D_FEAT + i] = (float)acc[i] * FIXINV;
        #undef GATHER
    } else {
        // ---- oversized-bucket fallback (statistically never; correct) ----
        #define GATHER(t) (USE16 \
            ? __uint_as_float((unsigned)emb16[(size_t)((t) & 0x1FFFF) * D_FEAT + lane] << 16) \
            : embeds[(size_t)((t) & 0x1FFFF) * D_FEAT + lane])
        for (int i = tid; i < nrows * D_FEAT; i += 512)
            out[(size_t)rowbase * D_FEAT + i] = 0.0f;
        __syncthreads();
        for (int seg = wid; seg < PB; seg += 8) {
            int len = sLen[seg];
            const u64* sp = sorted + (size_t)seg * chunk + sOff[seg];
            for (int i = 0; i < len; ++i) {
                u64 ent = sp[i];
                int lr = (int)((ent >> 17) & (ROWS_PER_BUCKET - 1));
                float v = __uint_as_float((unsigned)(ent >> 32));
                float m = GATHER(ent);
                atomicAdd(&out[(size_t)(rowbase + lr) * D_FEAT + lane], v * m);
            }
        }
        #undef GATHER
    }
}

extern "C" void kernel_launch(void* const* d_in, const int* in_sizes, int n_in,
                              void* d_out, int out_size, void* d_ws, size_t ws_size,
                              hipStream_t stream) {
    const int*   rows   = (const int*)d_in[0];
    const int*   cols   = (const int*)d_in[1];
    const float* vals   = (const float*)d_in[2];
    const float* embeds = (const float*)d_in[3];

    float* out = (float*)d_out;
    int n_edges = in_sizes[0];
    int n_nodes = out_size / D_FEAT;
    int n_buckets = (n_nodes + ROWS_PER_BUCKET - 1) >> LOG_RPB;
    int chunk = (n_edges + PB - 1) / PB;
    int n_elems = n_nodes * D_FEAT;

    // ws layout: [sorted: E u64][offg: (B+1)*PB ints][emb16: n_elems u16]
    size_t base_need = (size_t)n_edges * sizeof(u64) +
                       (size_t)(N_BUCKETS + 1) * PB * sizeof(int) + 256;
    size_t full_need = base_need + (size_t)n_elems * sizeof(unsigned short) + 256;

    if (n_buckets != N_BUCKETS || chunk > K1_CAP || chunk > EPT * K1_THREADS ||
        ws_size < base_need) {
        hipMemsetAsync(out, 0, (size_t)out_size * sizeof(float), stream);
        long long total_threads = (long long)n_edges * 16;
        int block = 256;
        int grid = (int)((total_threads + block - 1) / block);
        gcn_scatter_fallback<<<grid, block, 0, stream>>>(rows, cols, vals, embeds, out, n_edges);
        return;
    }

    u64* sorted = (u64*)d_ws;
    int* offg   = (int*)(sorted + n_edges);                  // [B+1][PB] transposed
    unsigned short* emb16 = (unsigned short*)
        (((uintptr_t)(offg + (size_t)(N_BUCKETS + 1) * PB) + 15) & ~(uintptr_t)15);

    bool use16 = (ws_size >= full_need);

    k_partition_conv<<<PB, K1_THREADS, 0, stream>>>(rows, cols, vals, sorted, offg,
                                                    embeds, emb16, use16 ? 1 : 0,
                                                    n_edges, n_elems, chunk);
    if (use16)
        k_aggregate_iatomic<true><<<N_BUCKETS, 512, 0, stream>>>(
            sorted, offg, embeds, emb16, out, n_nodes, chunk);
    else
        k_aggregate_iatomic<false><<<N_BUCKETS, 512, 0, stream>>>(
            sorted, offg, embeds, emb16, out, n_nodes, chunk);
}

// Round 9
// 147.276 us; speedup vs baseline: 5.3464x; 1.0709x over previous
//
#include <hip/hip_runtime.h>
#include <hip/hip_bf16.h>

// GCN sparse aggregation: out[rows[e], :] += vals[e] * embeds[cols[e], :]
// E = 1.6M, N = 100K, D = 64, fp32.
//
// Round 20: revert to round-17 K2 (sort + register agg, 47us; round-19's
// stream+ds_add_u32 lost 31% purely to occupancy: LDS 64KB -> 16 waves/CU
// vs 24, gather-latency-bound phase tracks waves ~linearly). Lever:
// RESIDENCY + BALANCE, not per-edge ops.
//  - ROWS_PER_BUCKET 128 -> 64: N_BUCKETS 782 -> 1563, K4_CAP 1536,
//    K2 LDS 33.8KB -> ~18.3KB. Blocks/CU still thread-capped at 4, but
//    now 1563 half-size tasks over 1024 slots: ~2.5 queued per CU
//    backfill dynamically -> steady ~32 waves/CU (was: all-resident
//    3.05/CU avg, max-4 imbalance, CUs drain to idle; measured 47%).
//  - K1 mechanical: 6-bit local row in meta, 1563-counter scan
//    (25 wave-segments), lh/cur 2x6.1KB, LDS 61.3KB (< 64KB cap).
//  Everything else verbatim round 17.

#define D_FEAT 64
#define LOG_RPB 6
#define ROWS_PER_BUCKET 64
#define N_BUCKETS 1563         // ceil(100000 / 64); guarded at runtime
#define PB 256                 // partition chunks / blocks
#define K1_THREADS 1024
#define K1_CAP 6272            // LDS chunk buffer (chunk = 6250 for E=1.6M)
#define EPT 7                  // edges per thread in partition (6250/1024)
#define K4_CAP 1536            // agg LDS buffer (bucket mean 1024, +16 sigma)
#define EPT2 3                 // K4_CAP / 512

typedef unsigned long long u64;

__device__ inline unsigned bf16rne(float x) {
    unsigned u = __float_as_uint(x);
    return (u + 0x7FFFu + ((u >> 16) & 1u)) >> 16;
}

__device__ inline int wave_incl_scan(int x, int lane) {
    #pragma unroll
    for (int o = 1; o < 64; o <<= 1) {
        int y = __shfl_up(x, o, 64);
        if (lane >= o) x += y;
    }
    return x;
}

// ---------------- fallback (round-1 atomic path) ----------------
__global__ __launch_bounds__(256) void gcn_scatter_fallback(
    const int* __restrict__ rows, const int* __restrict__ cols,
    const float* __restrict__ vals, const float* __restrict__ embeds,
    float* __restrict__ out, int n_edges)
{
    int gtid = blockIdx.x * blockDim.x + threadIdx.x;
    int e = gtid >> 4;
    if (e >= n_edges) return;
    int lane4 = gtid & 15;
    int row = rows[e]; int col = cols[e]; float v = vals[e];
    const float4* ep = reinterpret_cast<const float4*>(embeds + (size_t)col * D_FEAT);
    float4 m = ep[lane4];
    float* op = out + (size_t)row * D_FEAT + lane4 * 4;
    atomicAdd(op + 0, v * m.x);
    atomicAdd(op + 1, v * m.y);
    atomicAdd(op + 2, v * m.z);
    atomicAdd(op + 3, v * m.w);
}

// ---------------- K1: per-chunk counting sort + coalesced dump + convert ----------------
// 256 blocks x 1024 thr; 61.3KB LDS.
__global__ __launch_bounds__(1024, 4) void k_partition_conv(
    const int* __restrict__ rows, const int* __restrict__ cols,
    const float* __restrict__ vals, u64* __restrict__ sorted,
    int* __restrict__ offg, const float* __restrict__ embeds,
    unsigned short* __restrict__ emb16, int do_conv,
    int n_edges, int n_elems, int chunk)
{
    __shared__ u64 ebuf[K1_CAP];          // 50,176 B
    __shared__ int lh[N_BUCKETS];         //  6,252 B
    __shared__ int cur[N_BUCKETS];        //  6,252 B
    __shared__ int segtot[32];

    int blk = blockIdx.x, tid = threadIdx.x;
    int lane = tid & 63, wid = tid >> 6;     // 16 waves
    int beg = blk * chunk;
    int end = min(beg + chunk, n_edges);
    int cnt = end - beg;

    for (int i = tid; i < N_BUCKETS; i += K1_THREADS) lh[i] = 0;
    __syncthreads();

    // load edges into registers + bucket histogram (LDS int atomics)
    u64 ent[EPT]; int eb[EPT]; bool okk[EPT];
    #pragma unroll
    for (int k = 0; k < EPT; ++k) {
        int e = beg + k * K1_THREADS + tid;
        okk[k] = (e < end);
        if (okk[k]) {
            int r = rows[e];
            eb[k] = r >> LOG_RPB;
            unsigned meta = (unsigned)cols[e] |
                            ((unsigned)(r & (ROWS_PER_BUCKET - 1)) << 17);
            ent[k] = ((u64)__float_as_uint(vals[e]) << 32) | meta;
            atomicAdd(&lh[eb[k]], 1);
        }
    }
    __syncthreads();

    // in-LDS scan of 1563 counters (25 wave-segments over 16 waves)
    for (int seg = wid; seg * 64 < N_BUCKETS; seg += 16) {
        int idx = seg * 64 + lane;
        int v = (idx < N_BUCKETS) ? lh[idx] : 0;
        int inc = wave_incl_scan(v, lane);
        if (idx < N_BUCKETS) lh[idx] = inc - v;
        if (lane == 63) segtot[seg] = inc;
    }
    __syncthreads();
    if (tid < 64) {
        int v = (tid < 25) ? segtot[tid] : 0;
        int inc = wave_incl_scan(v, tid);
        if (tid < 25) segtot[tid] = inc - v;
    }
    __syncthreads();
    // offsets: TRANSPOSED global table offg[bucket][chunk] (L2-resident)
    for (int i = tid; i < N_BUCKETS; i += K1_THREADS) {
        int excl = lh[i] + segtot[i >> 6];
        offg[(size_t)i * PB + blk] = excl;
        cur[i] = excl;
    }
    if (tid == 0) offg[(size_t)N_BUCKETS * PB + blk] = cnt;
    __syncthreads();

    // scatter from REGISTERS into LDS bucket-sorted
    #pragma unroll
    for (int k = 0; k < EPT; ++k) {
        if (okk[k]) {
            int p = atomicAdd(&cur[eb[k]], 1);   // LDS int atomic only
            ebuf[p] = ent[k];
        }
    }
    __syncthreads();

    // dump: fully coalesced linear copy
    for (int i = tid; i < cnt; i += K1_THREADS)
        sorted[beg + i] = ebuf[i];

    // convert slice fp32 -> bf16 (packed, independent; overlaps tail)
    if (do_conv) {
        const float4* src4 = (const float4*)embeds;
        u64* dst4 = (u64*)emb16;
        int nq = n_elems >> 2;
        for (int i = blk * K1_THREADS + tid; i < nq; i += PB * K1_THREADS) {
            float4 f = src4[i];
            u64 pk = (u64)bf16rne(f.x) | ((u64)bf16rne(f.y) << 16) |
                     ((u64)bf16rne(f.z) << 32) | ((u64)bf16rne(f.w) << 48);
            dst4[i] = pk;
        }
        if (blk == 0 && tid < (n_elems & 3)) {
            int i = (nq << 2) + tid;
            emb16[i] = (unsigned short)bf16rne(embeds[i]);
        }
    }
}

// ---------------- K2: flat-indexed single-pass gather + counting sort + register agg ----------------
template <bool USE16>
__global__ __launch_bounds__(512) void k_aggregate_seg(
    const u64* __restrict__ sorted, const int* __restrict__ offg,
    const float* __restrict__ embeds, const unsigned short* __restrict__ emb16,
    float* __restrict__ out, int n_nodes, int chunk)
{
    __shared__ u64 ebuf[K4_CAP];                  // 12 KB
    __shared__ int sOff[PB], sLen[PB];            //  2 KB
    __shared__ int pre[PB + 1];                   //  1 KB (flat prefix)
    __shared__ int base[PB];                      //  1 KB (addr base per seg)
    __shared__ unsigned char segid[K4_CAP];       //  1.5 KB (flat idx -> seg)
    __shared__ int wtot[4], wpre[4];
    __shared__ int rcnt[ROWS_PER_BUCKET];
    __shared__ int roff[ROWS_PER_BUCKET + 1];
    __shared__ int rcur[ROWS_PER_BUCKET];

    int b = blockIdx.x, tid = threadIdx.x;
    int lane = tid & 63, wid = tid >> 6;   // 8 waves
    int rowbase = b * ROWS_PER_BUCKET;
    int nrows = n_nodes - rowbase;
    if (nrows > ROWS_PER_BUCKET) nrows = ROWS_PER_BUCKET;

    // ---- segment descriptors: two CONTIGUOUS 1KB runs (transposed table) ----
    if (tid < PB) {
        int o0 = offg[(size_t)b * PB + tid];
        int o1 = offg[(size_t)(b + 1) * PB + tid];
        sOff[tid] = o0;
        sLen[tid] = o1 - o0;
    }
    if (tid < ROWS_PER_BUCKET) rcnt[tid] = 0;
    __syncthreads();

    // ---- exclusive prefix of sLen -> pre[0..PB], n = pre[PB] ----
    if (wid < 4) {
        int v = sLen[wid * 64 + lane];
        int inc = wave_incl_scan(v, lane);
        pre[wid * 64 + lane] = inc - v;
        if (lane == 63) wtot[wid] = inc;
    }
    __syncthreads();
    if (tid == 0) {
        int a = 0;
        #pragma unroll
        for (int j = 0; j < 4; ++j) { wpre[j] = a; a += wtot[j]; }
        pre[PB] = a;
    }
    __syncthreads();
    if (tid < PB) pre[tid] += wpre[tid >> 6];
    __syncthreads();
    int n = pre[PB];

    if (n <= K4_CAP) {
        // ---- build segid/base lookup (replaces per-entry binary search) ----
        if (tid < PB) {
            int p0 = pre[tid];
            int p1 = pre[tid + 1];
            base[tid] = tid * chunk + sOff[tid] - p0;
            for (int j = p0; j < p1; ++j) segid[j] = (unsigned char)tid;
        }
        __syncthreads();

        // ---- single global pass: flat-indexed coalesced loads into registers ----
        u64 ent[EPT2];
        #pragma unroll
        for (int k = 0; k < EPT2; ++k) {
            int i = tid + k * 512;
            if (i < n) {
                int s = segid[i];
                ent[k] = sorted[(size_t)(base[s] + i)];
            }
        }
        // ---- histogram from registers ----
        #pragma unroll
        for (int k = 0; k < EPT2; ++k) {
            int i = tid + k * 512;
            if (i < n)
                atomicAdd(&rcnt[(int)((ent[k] >> 17) & (ROWS_PER_BUCKET - 1))], 1);
        }
        __syncthreads();

        // ---- scan of 64 counters by wave 0 ----
        if (tid < 64) {
            int a = rcnt[tid];
            int ia = wave_incl_scan(a, tid);
            roff[tid] = ia - a;
            rcur[tid] = ia - a;
            if (tid == 63) roff[ROWS_PER_BUCKET] = ia;
        }
        __syncthreads();

        // ---- scatter from REGISTERS row-sorted into ebuf ----
        #pragma unroll
        for (int k = 0; k < EPT2; ++k) {
            int i = tid + k * 512;
            if (i < n) {
                int lr = (int)((ent[k] >> 17) & (ROWS_PER_BUCKET - 1));
                int p = atomicAdd(&rcur[lr], 1);
                ebuf[p] = ent[k];
            }
        }
        __syncthreads();

        // ---- aggregate: wave w owns rows {w, w+8, ...}; lane = feature ----
        for (int lr = wid; lr < ROWS_PER_BUCKET; lr += 8) {
            int rs = roff[lr], re = roff[lr + 1];
            float acc = 0.0f;
            int j = rs;
            #define GATHER(t) (USE16 \
                ? __uint_as_float((unsigned)emb16[(size_t)((t) & 0x1FFFF) * D_FEAT + lane] << 16) \
                : embeds[(size_t)((t) & 0x1FFFF) * D_FEAT + lane])
            for (; j + 7 < re; j += 8) {
                u64 t0 = ebuf[j + 0], t1 = ebuf[j + 1], t2 = ebuf[j + 2], t3 = ebuf[j + 3];
                u64 t4 = ebuf[j + 4], t5 = ebuf[j + 5], t6 = ebuf[j + 6], t7 = ebuf[j + 7];
                float m0 = GATHER(t0), m1 = GATHER(t1), m2 = GATHER(t2), m3 = GATHER(t3);
                float m4 = GATHER(t4), m5 = GATHER(t5), m6 = GATHER(t6), m7 = GATHER(t7);
                acc += __uint_as_float((unsigned)(t0 >> 32)) * m0;
                acc += __uint_as_float((unsigned)(t1 >> 32)) * m1;
                acc += __uint_as_float((unsigned)(t2 >> 32)) * m2;
                acc += __uint_as_float((unsigned)(t3 >> 32)) * m3;
                acc += __uint_as_float((unsigned)(t4 >> 32)) * m4;
                acc += __uint_as_float((unsigned)(t5 >> 32)) * m5;
                acc += __uint_as_float((unsigned)(t6 >> 32)) * m6;
                acc += __uint_as_float((unsigned)(t7 >> 32)) * m7;
            }
            for (; j + 3 < re; j += 4) {
                u64 t0 = ebuf[j + 0], t1 = ebuf[j + 1], t2 = ebuf[j + 2], t3 = ebuf[j + 3];
                float m0 = GATHER(t0), m1 = GATHER(t1), m2 = GATHER(t2), m3 = GATHER(t3);
                acc += __uint_as_float((unsigned)(t0 >> 32)) * m0;
                acc += __uint_as_float((unsigned)(t1 >> 32)) * m1;
                acc += __uint_as_float((unsigned)(t2 >> 32)) * m2;
                acc += __uint_as_float((unsigned)(t3 >> 32)) * m3;
            }
            for (; j < re; ++j) {
                u64 t0 = ebuf[j];
                acc += __uint_as_float((unsigned)(t0 >> 32)) * GATHER(t0);
            }
            #undef GATHER
            if (lr < nrows)
                out[(size_t)(rowbase + lr) * D_FEAT + lane] = acc;
        }
    } else {
        // ---- oversized-bucket fallback (statistically never; correct) ----
        for (int i = tid; i < nrows * D_FEAT; i += 512)
            out[(size_t)rowbase * D_FEAT + i] = 0.0f;
        __syncthreads();
        for (int seg = wid; seg < PB; seg += 8) {
            int len = sLen[seg];
            const u64* sp = sorted + (size_t)seg * chunk + sOff[seg];
            for (int i = 0; i < len; ++i) {
                u64 ent = sp[i];
                int lr = (int)((ent >> 17) & (ROWS_PER_BUCKET - 1));
                int c = (int)(ent & 0x1FFFF);
                float v = __uint_as_float((unsigned)(ent >> 32));
                float m = embeds[(size_t)c * D_FEAT + lane];
                atomicAdd(&out[(size_t)(rowbase + lr) * D_FEAT + lane], v * m);
            }
        }
    }
}

extern "C" void kernel_launch(void* const* d_in, const int* in_sizes, int n_in,
                              void* d_out, int out_size, void* d_ws, size_t ws_size,
                              hipStream_t stream) {
    const int*   rows   = (const int*)d_in[0];
    const int*   cols   = (const int*)d_in[1];
    const float* vals   = (const float*)d_in[2];
    const float* embeds = (const float*)d_in[3];

    float* out = (float*)d_out;
    int n_edges = in_sizes[0];
    int n_nodes = out_size / D_FEAT;
    int n_buckets = (n_nodes + ROWS_PER_BUCKET - 1) >> LOG_RPB;
    int chunk = (n_edges + PB - 1) / PB;
    int n_elems = n_nodes * D_FEAT;

    // ws layout: [sorted: E u64][offg: (B+1)*PB ints][emb16: n_elems u16]
    size_t base_need = (size_t)n_edges * sizeof(u64) +
                       (size_t)(N_BUCKETS + 1) * PB * sizeof(int) + 256;
    size_t full_need = base_need + (size_t)n_elems * sizeof(unsigned short) + 256;

    if (n_buckets != N_BUCKETS || chunk > K1_CAP || chunk > EPT * K1_THREADS ||
        ws_size < base_need) {
        hipMemsetAsync(out, 0, (size_t)out_size * sizeof(float), stream);
        long long total_threads = (long long)n_edges * 16;
        int block = 256;
        int grid = (int)((total_threads + block - 1) / block);
        gcn_scatter_fallback<<<grid, block, 0, stream>>>(rows, cols, vals, embeds, out, n_edges);
        return;
    }

    u64* sorted = (u64*)d_ws;
    int* offg   = (int*)(sorted + n_edges);                  // [B+1][PB] transposed
    unsigned short* emb16 = (unsigned short*)
        (((uintptr_t)(offg + (size_t)(N_BUCKETS + 1) * PB) + 15) & ~(uintptr_t)15);

    bool use16 = (ws_size >= full_need);

    k_partition_conv<<<PB, K1_THREADS, 0, stream>>>(rows, cols, vals, sorted, offg,
                                                    embeds, emb16, use16 ? 1 : 0,
                                                    n_edges, n_elems, chunk);
    if (use16)
        k_aggregate_seg<true><<<N_BUCKETS, 512, 0, stream>>>(
            sorted, offg, embeds, emb16, out, n_nodes, chunk);
    else
        k_aggregate_seg<false><<<N_BUCKETS, 512, 0, stream>>>(
            sorted, offg, embeds, emb16, out, n_nodes, chunk);
}

// Round 11
// 145.194 us; speedup vs baseline: 5.4231x; 1.0143x over previous
//
#include <hip/hip_runtime.h>
#include <hip/hip_bf16.h>

// GCN sparse aggregation: out[rows[e], :] += vals[e] * embeds[cols[e], :]
// E = 1.6M, N = 100K, D = 64, fp32.
//
// Round 22 = round 21 resubmitted (bench infra failed twice; no kernel
// verdict). Decisive K1-occupancy test:
//  - K1: 512 blocks x 1024 thr (was 256x1024), chunk 3125, EPT 4,
//    LDS 31.4KB, __launch_bounds__(1024,8) -> 2 blocks/CU co-resident
//    = 32 waves/CU. Every prior K1 variant ran 16 waves/CU; K1 sits
//    ~3x above its BW floor and latency-hiding is the untested lever.
//    E = 512*3125 exactly (no tail).
//  - K2: PB=512 with the r17 machinery (contiguous transposed
//    descriptor runs, segid/base lookup -- no binary search). segid is
//    u16 (PB>255). Expected cost: flat-load run length 8 -> 4,
//    ~+2-3us. All else verbatim round 17.
//  Decision rule: e2e <= ~135 confirms K1 latency-bound (keep pushing
//  K1); e2e >= ~144 kills the hypothesis -> revert to r17, declare.

#define D_FEAT 64
#define LOG_RPB 7
#define ROWS_PER_BUCKET 128
#define N_BUCKETS 782          // ceil(100000 / 128); guarded at runtime
#define PB 512                 // partition chunks / blocks
#define K1_THREADS 1024
#define K1_CAP 3136            // LDS chunk buffer (chunk = 3125 for E=1.6M)
#define EPT 4                  // ceil(3125 / 1024)
#define K4_CAP 3072            // agg LDS buffer (bucket mean 2046, +22 sigma)
#define EPT2 6                 // K4_CAP / 512

typedef unsigned long long u64;

__device__ inline unsigned bf16rne(float x) {
    unsigned u = __float_as_uint(x);
    return (u + 0x7FFFu + ((u >> 16) & 1u)) >> 16;
}

__device__ inline int wave_incl_scan(int x, int lane) {
    #pragma unroll
    for (int o = 1; o < 64; o <<= 1) {
        int y = __shfl_up(x, o, 64);
        if (lane >= o) x += y;
    }
    return x;
}

// ---------------- fallback (round-1 atomic path) ----------------
__global__ __launch_bounds__(256) void gcn_scatter_fallback(
    const int* __restrict__ rows, const int* __restrict__ cols,
    const float* __restrict__ vals, const float* __restrict__ embeds,
    float* __restrict__ out, int n_edges)
{
    int gtid = blockIdx.x * blockDim.x + threadIdx.x;
    int e = gtid >> 4;
    if (e >= n_edges) return;
    int lane4 = gtid & 15;
    int row = rows[e]; int col = cols[e]; float v = vals[e];
    const float4* ep = reinterpret_cast<const float4*>(embeds + (size_t)col * D_FEAT);
    float4 m = ep[lane4];
    float* op = out + (size_t)row * D_FEAT + lane4 * 4;
    atomicAdd(op + 0, v * m.x);
    atomicAdd(op + 1, v * m.y);
    atomicAdd(op + 2, v * m.z);
    atomicAdd(op + 3, v * m.w);
}

// ---------------- K1: per-chunk counting sort + coalesced dump + convert ----------------
// 512 blocks x 1024 thr; 31.4KB LDS -> 2 blocks/CU = 32 waves/CU.
__global__ __launch_bounds__(1024, 8) void k_partition_conv(
    const int* __restrict__ rows, const int* __restrict__ cols,
    const float* __restrict__ vals, u64* __restrict__ sorted,
    int* __restrict__ offg, const float* __restrict__ embeds,
    unsigned short* __restrict__ emb16, int do_conv,
    int n_edges, int n_elems, int chunk)
{
    __shared__ u64 ebuf[K1_CAP];          // 25,088 B
    __shared__ int lh[N_BUCKETS];         //  3,128 B
    __shared__ int cur[N_BUCKETS];        //  3,128 B
    __shared__ int segtot[16];

    int blk = blockIdx.x, tid = threadIdx.x;
    int lane = tid & 63, wid = tid >> 6;     // 16 waves
    int beg = blk * chunk;
    int end = min(beg + chunk, n_edges);
    int cnt = end - beg;

    for (int i = tid; i < N_BUCKETS; i += K1_THREADS) lh[i] = 0;
    __syncthreads();

    // load edges into registers + bucket histogram (LDS int atomics)
    u64 ent[EPT]; int eb[EPT]; bool okk[EPT];
    #pragma unroll
    for (int k = 0; k < EPT; ++k) {
        int e = beg + k * K1_THREADS + tid;
        okk[k] = (e < end);
        if (okk[k]) {
            int r = rows[e];
            eb[k] = r >> LOG_RPB;
            unsigned meta = (unsigned)cols[e] |
                            ((unsigned)(r & (ROWS_PER_BUCKET - 1)) << 17);
            ent[k] = ((u64)__float_as_uint(vals[e]) << 32) | meta;
            atomicAdd(&lh[eb[k]], 1);
        }
    }
    __syncthreads();

    // in-LDS scan of 782 counters (13 wave-segments over 16 waves)
    for (int seg = wid; seg * 64 < N_BUCKETS; seg += 16) {
        int idx = seg * 64 + lane;
        int v = (idx < N_BUCKETS) ? lh[idx] : 0;
        int inc = wave_incl_scan(v, lane);
        if (idx < N_BUCKETS) lh[idx] = inc - v;
        if (lane == 63) segtot[seg] = inc;
    }
    __syncthreads();
    if (tid < 64) {
        int v = (tid < 13) ? segtot[tid] : 0;
        int inc = wave_incl_scan(v, tid);
        if (tid < 13) segtot[tid] = inc - v;
    }
    __syncthreads();
    // offsets: TRANSPOSED global table offg[bucket][chunk] (L2-resident)
    for (int i = tid; i < N_BUCKETS; i += K1_THREADS) {
        int excl = lh[i] + segtot[i >> 6];
        offg[(size_t)i * PB + blk] = excl;
        cur[i] = excl;
    }
    if (tid == 0) offg[(size_t)N_BUCKETS * PB + blk] = cnt;
    __syncthreads();

    // scatter from REGISTERS into LDS bucket-sorted
    #pragma unroll
    for (int k = 0; k < EPT; ++k) {
        if (okk[k]) {
            int p = atomicAdd(&cur[eb[k]], 1);   // LDS int atomic only
            ebuf[p] = ent[k];
        }
    }
    __syncthreads();

    // dump: fully coalesced linear copy
    for (int i = tid; i < cnt; i += K1_THREADS)
        sorted[beg + i] = ebuf[i];

    // convert slice fp32 -> bf16 (packed, independent; overlaps tail)
    if (do_conv) {
        const float4* src4 = (const float4*)embeds;
        u64* dst4 = (u64*)emb16;
        int nq = n_elems >> 2;
        for (int i = blk * K1_THREADS + tid; i < nq; i += PB * K1_THREADS) {
            float4 f = src4[i];
            u64 pk = (u64)bf16rne(f.x) | ((u64)bf16rne(f.y) << 16) |
                     ((u64)bf16rne(f.z) << 32) | ((u64)bf16rne(f.w) << 48);
            dst4[i] = pk;
        }
        if (blk == 0 && tid < (n_elems & 3)) {
            int i = (nq << 2) + tid;
            emb16[i] = (unsigned short)bf16rne(embeds[i]);
        }
    }
}

// ---------------- K2: flat-indexed single-pass gather + counting sort + register agg ----------------
template <bool USE16>
__global__ __launch_bounds__(512) void k_aggregate_seg(
    const u64* __restrict__ sorted, const int* __restrict__ offg,
    const float* __restrict__ embeds, const unsigned short* __restrict__ emb16,
    float* __restrict__ out, int n_nodes, int chunk)
{
    __shared__ u64 ebuf[K4_CAP];                  // 24 KB
    __shared__ int sOff[PB], sLen[PB];            //  4 KB
    __shared__ int pre[PB + 1];                   //  2 KB (flat prefix)
    __shared__ int base[PB];                      //  2 KB (addr base per seg)
    __shared__ unsigned short segid[K4_CAP];      //  6 KB (flat idx -> seg)
    __shared__ int wtot[8], wpre[8];
    __shared__ int rcnt[ROWS_PER_BUCKET];
    __shared__ int roff[ROWS_PER_BUCKET + 1];
    __shared__ int rcur[ROWS_PER_BUCKET];

    int b = blockIdx.x, tid = threadIdx.x;
    int lane = tid & 63, wid = tid >> 6;   // 8 waves
    int rowbase = b * ROWS_PER_BUCKET;
    int nrows = n_nodes - rowbase;
    if (nrows > ROWS_PER_BUCKET) nrows = ROWS_PER_BUCKET;

    // ---- segment descriptors: two CONTIGUOUS 2KB runs (transposed table) ----
    {
        int o0 = offg[(size_t)b * PB + tid];
        int o1 = offg[(size_t)(b + 1) * PB + tid];
        sOff[tid] = o0;
        sLen[tid] = o1 - o0;
    }
    for (int i = tid; i < ROWS_PER_BUCKET; i += 512) rcnt[i] = 0;
    __syncthreads();

    // ---- exclusive prefix of sLen -> pre[0..PB], n = pre[PB] ----
    {
        int v = sLen[tid];
        int inc = wave_incl_scan(v, lane);
        pre[tid] = inc - v;
        if (lane == 63) wtot[wid] = inc;
    }
    __syncthreads();
    if (tid == 0) {
        int a = 0;
        #pragma unroll
        for (int j = 0; j < 8; ++j) { wpre[j] = a; a += wtot[j]; }
        pre[PB] = a;
    }
    __syncthreads();
    pre[tid] += wpre[tid >> 6];
    __syncthreads();
    int n = pre[PB];

    if (n <= K4_CAP) {
        // ---- build segid/base lookup (no binary search) ----
        {
            int p0 = pre[tid];
            int p1 = pre[tid + 1];
            base[tid] = tid * chunk + sOff[tid] - p0;
            for (int j = p0; j < p1; ++j) segid[j] = (unsigned short)tid;
        }
        __syncthreads();

        // ---- single global pass: flat-indexed coalesced loads into registers ----
        u64 ent[EPT2];
        #pragma unroll
        for (int k = 0; k < EPT2; ++k) {
            int i = tid + k * 512;
            if (i < n) {
                int s = segid[i];
                ent[k] = sorted[(size_t)(base[s] + i)];
            }
        }
        // ---- histogram from registers ----
        #pragma unroll
        for (int k = 0; k < EPT2; ++k) {
            int i = tid + k * 512;
            if (i < n)
                atomicAdd(&rcnt[(int)((ent[k] >> 17) & (ROWS_PER_BUCKET - 1))], 1);
        }
        __syncthreads();

        // ---- scan of 128 counters by wave 0 ----
        if (tid < 64) {
            int a = rcnt[tid], c = rcnt[64 + tid];
            int ia = wave_incl_scan(a, tid);
            int ta = __shfl(ia, 63, 64);
            int ic = wave_incl_scan(c, tid);
            int ea = ia - a;
            int ec = ta + ic - c;
            roff[tid] = ea;       rcur[tid] = ea;
            roff[64 + tid] = ec;  rcur[64 + tid] = ec;
            if (tid == 63) roff[ROWS_PER_BUCKET] = ta + __shfl(ic, 63, 64);
        }
        __syncthreads();

        // ---- scatter from REGISTERS row-sorted into ebuf ----
        #pragma unroll
        for (int k = 0; k < EPT2; ++k) {
            int i = tid + k * 512;
            if (i < n) {
                int lr = (int)((ent[k] >> 17) & (ROWS_PER_BUCKET - 1));
                int p = atomicAdd(&rcur[lr], 1);
                ebuf[p] = ent[k];
            }
        }
        __syncthreads();

        // ---- aggregate: wave w owns rows {w, w+8, ...}; lane = feature ----
        for (int lr = wid; lr < ROWS_PER_BUCKET; lr += 8) {
            int rs = roff[lr], re = roff[lr + 1];
            float acc = 0.0f;
            int j = rs;
            #define GATHER(t) (USE16 \
                ? __uint_as_float((unsigned)emb16[(size_t)((t) & 0x1FFFF) * D_FEAT + lane] << 16) \
                : embeds[(size_t)((t) & 0x1FFFF) * D_FEAT + lane])
            for (; j + 7 < re; j += 8) {
                u64 t0 = ebuf[j + 0], t1 = ebuf[j + 1], t2 = ebuf[j + 2], t3 = ebuf[j + 3];
                u64 t4 = ebuf[j + 4], t5 = ebuf[j + 5], t6 = ebuf[j + 6], t7 = ebuf[j + 7];
                float m0 = GATHER(t0), m1 = GATHER(t1), m2 = GATHER(t2), m3 = GATHER(t3);
                float m4 = GATHER(t4), m5 = GATHER(t5), m6 = GATHER(t6), m7 = GATHER(t7);
                acc += __uint_as_float((unsigned)(t0 >> 32)) * m0;
                acc += __uint_as_float((unsigned)(t1 >> 32)) * m1;
                acc += __uint_as_float((unsigned)(t2 >> 32)) * m2;
                acc += __uint_as_float((unsigned)(t3 >> 32)) * m3;
                acc += __uint_as_float((unsigned)(t4 >> 32)) * m4;
                acc += __uint_as_float((unsigned)(t5 >> 32)) * m5;
                acc += __uint_as_float((unsigned)(t6 >> 32)) * m6;
                acc += __uint_as_float((unsigned)(t7 >> 32)) * m7;
            }
            for (; j + 3 < re; j += 4) {
                u64 t0 = ebuf[j + 0], t1 = ebuf[j + 1], t2 = ebuf[j + 2], t3 = ebuf[j + 3];
                float m0 = GATHER(t0), m1 = GATHER(t1), m2 = GATHER(t2), m3 = GATHER(t3);
                acc += __uint_as_float((unsigned)(t0 >> 32)) * m0;
                acc += __uint_as_float((unsigned)(t1 >> 32)) * m1;
                acc += __uint_as_float((unsigned)(t2 >> 32)) * m2;
                acc += __uint_as_float((unsigned)(t3 >> 32)) * m3;
            }
            for (; j < re; ++j) {
                u64 t0 = ebuf[j];
                acc += __uint_as_float((unsigned)(t0 >> 32)) * GATHER(t0);
            }
            #undef GATHER
            if (lr < nrows)
                out[(size_t)(rowbase + lr) * D_FEAT + lane] = acc;
        }
    } else {
        // ---- oversized-bucket fallback (statistically never; correct) ----
        for (int i = tid; i < nrows * D_FEAT; i += 512)
            out[(size_t)rowbase * D_FEAT + i] = 0.0f;
        __syncthreads();
        for (int seg = wid; seg < PB; seg += 8) {
            int len = sLen[seg];
            const u64* sp = sorted + (size_t)seg * chunk + sOff[seg];
            for (int i = 0; i < len; ++i) {
                u64 ent = sp[i];
                int lr = (int)((ent >> 17) & (ROWS_PER_BUCKET - 1));
                int c = (int)(ent & 0x1FFFF);
                float v = __uint_as_float((unsigned)(ent >> 32));
                float m = embeds[(size_t)c * D_FEAT + lane];
                atomicAdd(&out[(size_t)(rowbase + lr) * D_FEAT + lane], v * m);
            }
        }
    }
}

extern "C" void kernel_launch(void* const* d_in, const int* in_sizes, int n_in,
                              void* d_out, int out_size, void* d_ws, size_t ws_size,
                              hipStream_t stream) {
    const int*   rows   = (const int*)d_in[0];
    const int*   cols   = (const int*)d_in[1];
    const float* vals   = (const float*)d_in[2];
    const float* embeds = (const float*)d_in[3];

    float* out = (float*)d_out;
    int n_edges = in_sizes[0];
    int n_nodes = out_size / D_FEAT;
    int n_buckets = (n_nodes + ROWS_PER_BUCKET - 1) >> LOG_RPB;
    int chunk = (n_edges + PB - 1) / PB;
    int n_elems = n_nodes * D_FEAT;

    // ws layout: [sorted: E u64][offg: (B+1)*PB ints][emb16: n_elems u16]
    size_t base_need = (size_t)n_edges * sizeof(u64) +
                       (size_t)(N_BUCKETS + 1) * PB * sizeof(int) + 256;
    size_t full_need = base_need + (size_t)n_elems * sizeof(unsigned short) + 256;

    if (n_buckets != N_BUCKETS || chunk > K1_CAP || chunk > EPT * K1_THREADS ||
        ws_size < base_need) {
        hipMemsetAsync(out, 0, (size_t)out_size * sizeof(float), stream);
        long long total_threads = (long long)n_edges * 16;
        int block = 256;
        int grid = (int)((total_threads + block - 1) / block);
        gcn_scatter_fallback<<<grid, block, 0, stream>>>(rows, cols, vals, embeds, out, n_edges);
        return;
    }

    u64* sorted = (u64*)d_ws;
    int* offg   = (int*)(sorted + n_edges);                  // [B+1][PB] transposed
    unsigned short* emb16 = (unsigned short*)
        (((uintptr_t)(offg + (size_t)(N_BUCKETS + 1) * PB) + 15) & ~(uintptr_t)15);

    bool use16 = (ws_size >= full_need);

    k_partition_conv<<<PB, K1_THREADS, 0, stream>>>(rows, cols, vals, sorted, offg,
                                                    embeds, emb16, use16 ? 1 : 0,
                                                    n_edges, n_elems, chunk);
    if (use16)
        k_aggregate_seg<true><<<N_BUCKETS, 512, 0, stream>>>(
            sorted, offg, embeds, emb16, out, n_nodes, chunk);
    else
        k_aggregate_seg<false><<<N_BUCKETS, 512, 0, stream>>>(
            sorted, offg, embeds, emb16, out, n_nodes, chunk);
}

// Round 12
// 142.945 us; speedup vs baseline: 5.5084x; 1.0157x over previous
//
#include <hip/hip_runtime.h>
#include <hip/hip_bf16.h>

// GCN sparse aggregation: out[rows[e], :] += vals[e] * embeds[cols[e], :]
// E = 1.6M, N = 100K, D = 64, fp32.
//
// Round 23: REVERT to exact round-17 (measured best: 141.2us e2e;
// K2 47.0us, FETCH 92.7MB). Round-22's decisive K1-occupancy test
// (32 waves/CU) left the ~95us residual unchanged -> K1 is
// throughput-bound (LDS sort ops + streaming BW), not latency-bound;
// PB=512 costs K2 +2.7us. Structural alternatives all measured worse:
// LDS f32/int-atomic accumulators (690/704/61.5us), per-segment waves
// (100us), bucket-contiguous global (172us), half buckets (147us),
// PB=512 (147.7/145.2us). This geometry is the declaration candidate.
//
// Structure:
//  K1 k_partition_conv (256 blocks x 1024 thr): per-chunk LDS counting
//     sort by bucket (LDS int atomics only), TRANSPOSED offg[bucket][chunk]
//     descriptor table, coalesced dump, fused fp32->bf16 convert.
//  K2 k_aggregate_seg (782 blocks x 512 thr): contiguous descriptor
//     runs + segid/base lookup (no binary search), flat-indexed
//     coalesced single global pass into registers, in-LDS counting sort
//     by local row, per-row register accumulation (lane = feature),
//     coalesced 256B row stores. No fp atomics anywhere.

#define D_FEAT 64
#define LOG_RPB 7
#define ROWS_PER_BUCKET 128
#define N_BUCKETS 782          // ceil(100000 / 128); guarded at runtime
#define PB 256                 // partition chunks / blocks
#define K1_THREADS 1024
#define K1_CAP 6272            // LDS chunk buffer (chunk = 6250 for E=1.6M)
#define EPT 7                  // edges per thread in partition (6250/1024)
#define K4_CAP 3072            // agg LDS buffer (bucket mean 2046, +22 sigma)
#define EPT2 6                 // K4_CAP / 512

typedef unsigned long long u64;

__device__ inline unsigned bf16rne(float x) {
    unsigned u = __float_as_uint(x);
    return (u + 0x7FFFu + ((u >> 16) & 1u)) >> 16;
}

__device__ inline int wave_incl_scan(int x, int lane) {
    #pragma unroll
    for (int o = 1; o < 64; o <<= 1) {
        int y = __shfl_up(x, o, 64);
        if (lane >= o) x += y;
    }
    return x;
}

// ---------------- fallback (round-1 atomic path) ----------------
__global__ __launch_bounds__(256) void gcn_scatter_fallback(
    const int* __restrict__ rows, const int* __restrict__ cols,
    const float* __restrict__ vals, const float* __restrict__ embeds,
    float* __restrict__ out, int n_edges)
{
    int gtid = blockIdx.x * blockDim.x + threadIdx.x;
    int e = gtid >> 4;
    if (e >= n_edges) return;
    int lane4 = gtid & 15;
    int row = rows[e]; int col = cols[e]; float v = vals[e];
    const float4* ep = reinterpret_cast<const float4*>(embeds + (size_t)col * D_FEAT);
    float4 m = ep[lane4];
    float* op = out + (size_t)row * D_FEAT + lane4 * 4;
    atomicAdd(op + 0, v * m.x);
    atomicAdd(op + 1, v * m.y);
    atomicAdd(op + 2, v * m.z);
    atomicAdd(op + 3, v * m.w);
}

// ---------------- K1: per-chunk counting sort + coalesced dump + convert ----------------
// 256 blocks x 1024 thr; 56.5KB LDS.
__global__ __launch_bounds__(1024, 4) void k_partition_conv(
    const int* __restrict__ rows, const int* __restrict__ cols,
    const float* __restrict__ vals, u64* __restrict__ sorted,
    int* __restrict__ offg, const float* __restrict__ embeds,
    unsigned short* __restrict__ emb16, int do_conv,
    int n_edges, int n_elems, int chunk)
{
    __shared__ u64 ebuf[K1_CAP];          // 50,176 B
    __shared__ int lh[N_BUCKETS];         //  3,128 B
    __shared__ int cur[N_BUCKETS];        //  3,128 B
    __shared__ int segtot[16];

    int blk = blockIdx.x, tid = threadIdx.x;
    int lane = tid & 63, wid = tid >> 6;     // 16 waves
    int beg = blk * chunk;
    int end = min(beg + chunk, n_edges);
    int cnt = end - beg;

    for (int i = tid; i < N_BUCKETS; i += K1_THREADS) lh[i] = 0;
    __syncthreads();

    // load edges into registers + bucket histogram (LDS int atomics)
    u64 ent[EPT]; int eb[EPT]; bool okk[EPT];
    #pragma unroll
    for (int k = 0; k < EPT; ++k) {
        int e = beg + k * K1_THREADS + tid;
        okk[k] = (e < end);
        if (okk[k]) {
            int r = rows[e];
            eb[k] = r >> LOG_RPB;
            unsigned meta = (unsigned)cols[e] |
                            ((unsigned)(r & (ROWS_PER_BUCKET - 1)) << 17);
            ent[k] = ((u64)__float_as_uint(vals[e]) << 32) | meta;
            atomicAdd(&lh[eb[k]], 1);
        }
    }
    __syncthreads();

    // in-LDS scan of 782 counters (13 wave-segments over 16 waves)
    for (int seg = wid; seg * 64 < N_BUCKETS; seg += 16) {
        int idx = seg * 64 + lane;
        int v = (idx < N_BUCKETS) ? lh[idx] : 0;
        int inc = wave_incl_scan(v, lane);
        if (idx < N_BUCKETS) lh[idx] = inc - v;
        if (lane == 63) segtot[seg] = inc;
    }
    __syncthreads();
    if (tid < 64) {
        int v = (tid < 13) ? segtot[tid] : 0;
        int inc = wave_incl_scan(v, tid);
        if (tid < 13) segtot[tid] = inc - v;
    }
    __syncthreads();
    // offsets: TRANSPOSED global table offg[bucket][chunk] (L2-resident)
    for (int i = tid; i < N_BUCKETS; i += K1_THREADS) {
        int excl = lh[i] + segtot[i >> 6];
        offg[(size_t)i * PB + blk] = excl;
        cur[i] = excl;
    }
    if (tid == 0) offg[(size_t)N_BUCKETS * PB + blk] = cnt;
    __syncthreads();

    // scatter from REGISTERS into LDS bucket-sorted
    #pragma unroll
    for (int k = 0; k < EPT; ++k) {
        if (okk[k]) {
            int p = atomicAdd(&cur[eb[k]], 1);   // LDS int atomic only
            ebuf[p] = ent[k];
        }
    }
    __syncthreads();

    // dump: fully coalesced linear copy
    for (int i = tid; i < cnt; i += K1_THREADS)
        sorted[beg + i] = ebuf[i];

    // convert slice fp32 -> bf16 (packed, independent; overlaps tail)
    if (do_conv) {
        const float4* src4 = (const float4*)embeds;
        u64* dst4 = (u64*)emb16;
        int nq = n_elems >> 2;
        for (int i = blk * K1_THREADS + tid; i < nq; i += PB * K1_THREADS) {
            float4 f = src4[i];
            u64 pk = (u64)bf16rne(f.x) | ((u64)bf16rne(f.y) << 16) |
                     ((u64)bf16rne(f.z) << 32) | ((u64)bf16rne(f.w) << 48);
            dst4[i] = pk;
        }
        if (blk == 0 && tid < (n_elems & 3)) {
            int i = (nq << 2) + tid;
            emb16[i] = (unsigned short)bf16rne(embeds[i]);
        }
    }
}

// ---------------- K2: flat-indexed single-pass gather + counting sort + register agg ----------------
template <bool USE16>
__global__ __launch_bounds__(512) void k_aggregate_seg(
    const u64* __restrict__ sorted, const int* __restrict__ offg,
    const float* __restrict__ embeds, const unsigned short* __restrict__ emb16,
    float* __restrict__ out, int n_nodes, int chunk)
{
    __shared__ u64 ebuf[K4_CAP];                  // 24 KB
    __shared__ int sOff[PB], sLen[PB];            //  2 KB
    __shared__ int pre[PB + 1];                   //  1 KB (flat prefix)
    __shared__ int base[PB];                      //  1 KB (addr base per seg)
    __shared__ unsigned char segid[K4_CAP];       //  3 KB (flat idx -> seg)
    __shared__ int wtot[4], wpre[4];
    __shared__ int rcnt[ROWS_PER_BUCKET];
    __shared__ int roff[ROWS_PER_BUCKET + 1];
    __shared__ int rcur[ROWS_PER_BUCKET];

    int b = blockIdx.x, tid = threadIdx.x;
    int lane = tid & 63, wid = tid >> 6;   // 8 waves
    int rowbase = b * ROWS_PER_BUCKET;
    int nrows = n_nodes - rowbase;
    if (nrows > ROWS_PER_BUCKET) nrows = ROWS_PER_BUCKET;

    // ---- segment descriptors: two CONTIGUOUS 1KB runs (transposed table) ----
    if (tid < PB) {
        int o0 = offg[(size_t)b * PB + tid];
        int o1 = offg[(size_t)(b + 1) * PB + tid];
        sOff[tid] = o0;
        sLen[tid] = o1 - o0;
    }
    for (int i = tid; i < ROWS_PER_BUCKET; i += 512) rcnt[i] = 0;
    __syncthreads();

    // ---- exclusive prefix of sLen -> pre[0..PB], n = pre[PB] ----
    if (wid < 4) {
        int v = sLen[wid * 64 + lane];
        int inc = wave_incl_scan(v, lane);
        pre[wid * 64 + lane] = inc - v;
        if (lane == 63) wtot[wid] = inc;
    }
    __syncthreads();
    if (tid == 0) {
        int a = 0;
        #pragma unroll
        for (int j = 0; j < 4; ++j) { wpre[j] = a; a += wtot[j]; }
        pre[PB] = a;
    }
    __syncthreads();
    if (tid < PB) pre[tid] += wpre[tid >> 6];
    __syncthreads();
    int n = pre[PB];

    if (n <= K4_CAP) {
        // ---- build segid/base lookup (replaces per-entry binary search) ----
        if (tid < PB) {
            int p0 = pre[tid];
            int p1 = pre[tid + 1];
            base[tid] = tid * chunk + sOff[tid] - p0;
            for (int j = p0; j < p1; ++j) segid[j] = (unsigned char)tid;
        }
        __syncthreads();

        // ---- single global pass: flat-indexed coalesced loads into registers ----
        u64 ent[EPT2];
        #pragma unroll
        for (int k = 0; k < EPT2; ++k) {
            int i = tid + k * 512;
            if (i < n) {
                int s = segid[i];
                ent[k] = sorted[(size_t)(base[s] + i)];
            }
        }
        // ---- histogram from registers ----
        #pragma unroll
        for (int k = 0; k < EPT2; ++k) {
            int i = tid + k * 512;
            if (i < n)
                atomicAdd(&rcnt[(int)((ent[k] >> 17) & (ROWS_PER_BUCKET - 1))], 1);
        }
        __syncthreads();

        // ---- scan of 128 counters by wave 0 ----
        if (tid < 64) {
            int a = rcnt[tid], c = rcnt[64 + tid];
            int ia = wave_incl_scan(a, tid);
            int ta = __shfl(ia, 63, 64);
            int ic = wave_incl_scan(c, tid);
            int ea = ia - a;
            int ec = ta + ic - c;
            roff[tid] = ea;       rcur[tid] = ea;
            roff[64 + tid] = ec;  rcur[64 + tid] = ec;
            if (tid == 63) roff[ROWS_PER_BUCKET] = ta + __shfl(ic, 63, 64);
        }
        __syncthreads();

        // ---- scatter from REGISTERS row-sorted into ebuf ----
        #pragma unroll
        for (int k = 0; k < EPT2; ++k) {
            int i = tid + k * 512;
            if (i < n) {
                int lr = (int)((ent[k] >> 17) & (ROWS_PER_BUCKET - 1));
                int p = atomicAdd(&rcur[lr], 1);
                ebuf[p] = ent[k];
            }
        }
        __syncthreads();

        // ---- aggregate: wave w owns rows {w, w+8, ...}; lane = feature ----
        for (int lr = wid; lr < ROWS_PER_BUCKET; lr += 8) {
            int rs = roff[lr], re = roff[lr + 1];
            float acc = 0.0f;
            int j = rs;
            #define GATHER(t) (USE16 \
                ? __uint_as_float((unsigned)emb16[(size_t)((t) & 0x1FFFF) * D_FEAT + lane] << 16) \
                : embeds[(size_t)((t) & 0x1FFFF) * D_FEAT + lane])
            for (; j + 7 < re; j += 8) {
                u64 t0 = ebuf[j + 0], t1 = ebuf[j + 1], t2 = ebuf[j + 2], t3 = ebuf[j + 3];
                u64 t4 = ebuf[j + 4], t5 = ebuf[j + 5], t6 = ebuf[j + 6], t7 = ebuf[j + 7];
                float m0 = GATHER(t0), m1 = GATHER(t1), m2 = GATHER(t2), m3 = GATHER(t3);
                float m4 = GATHER(t4), m5 = GATHER(t5), m6 = GATHER(t6), m7 = GATHER(t7);
                acc += __uint_as_float((unsigned)(t0 >> 32)) * m0;
                acc += __uint_as_float((unsigned)(t1 >> 32)) * m1;
                acc += __uint_as_float((unsigned)(t2 >> 32)) * m2;
                acc += __uint_as_float((unsigned)(t3 >> 32)) * m3;
                acc += __uint_as_float((unsigned)(t4 >> 32)) * m4;
                acc += __uint_as_float((unsigned)(t5 >> 32)) * m5;
                acc += __uint_as_float((unsigned)(t6 >> 32)) * m6;
                acc += __uint_as_float((unsigned)(t7 >> 32)) * m7;
            }
            for (; j + 3 < re; j += 4) {
                u64 t0 = ebuf[j + 0], t1 = ebuf[j + 1], t2 = ebuf[j + 2], t3 = ebuf[j + 3];
                float m0 = GATHER(t0), m1 = GATHER(t1), m2 = GATHER(t2), m3 = GATHER(t3);
                acc += __uint_as_float((unsigned)(t0 >> 32)) * m0;
                acc += __uint_as_float((unsigned)(t1 >> 32)) * m1;
                acc += __uint_as_float((unsigned)(t2 >> 32)) * m2;
                acc += __uint_as_float((unsigned)(t3 >> 32)) * m3;
            }
            for (; j < re; ++j) {
                u64 t0 = ebuf[j];
                acc += __uint_as_float((unsigned)(t0 >> 32)) * GATHER(t0);
            }
            #undef GATHER
            if (lr < nrows)
                out[(size_t)(rowbase + lr) * D_FEAT + lane] = acc;
        }
    } else {
        // ---- oversized-bucket fallback (statistically never; correct) ----
        for (int i = tid; i < nrows * D_FEAT; i += 512)
            out[(size_t)rowbase * D_FEAT + i] = 0.0f;
        __syncthreads();
        for (int seg = wid; seg < PB; seg += 8) {
            int len = sLen[seg];
            const u64* sp = sorted + (size_t)seg * chunk + sOff[seg];
            for (int i = 0; i < len; ++i) {
                u64 ent = sp[i];
                int lr = (int)((ent >> 17) & (ROWS_PER_BUCKET - 1));
                int c = (int)(ent & 0x1FFFF);
                float v = __uint_as_float((unsigned)(ent >> 32));
                float m = embeds[(size_t)c * D_FEAT + lane];
                atomicAdd(&out[(size_t)(rowbase + lr) * D_FEAT + lane], v * m);
            }
        }
    }
}

extern "C" void kernel_launch(void* const* d_in, const int* in_sizes, int n_in,
                              void* d_out, int out_size, void* d_ws, size_t ws_size,
                              hipStream_t stream) {
    const int*   rows   = (const int*)d_in[0];
    const int*   cols   = (const int*)d_in[1];
    const float* vals   = (const float*)d_in[2];
    const float* embeds = (const float*)d_in[3];

    float* out = (float*)d_out;
    int n_edges = in_sizes[0];
    int n_nodes = out_size / D_FEAT;
    int n_buckets = (n_nodes + ROWS_PER_BUCKET - 1) >> LOG_RPB;
    int chunk = (n_edges + PB - 1) / PB;
    int n_elems = n_nodes * D_FEAT;

    // ws layout: [sorted: E u64][offg: (B+1)*PB ints][emb16: n_elems u16]
    size_t base_need = (size_t)n_edges * sizeof(u64) +
                       (size_t)(N_BUCKETS + 1) * PB * sizeof(int) + 256;
    size_t full_need = base_need + (size_t)n_elems * sizeof(unsigned short) + 256;

    if (n_buckets != N_BUCKETS || chunk > K1_CAP || chunk > EPT * K1_THREADS ||
        ws_size < base_need) {
        hipMemsetAsync(out, 0, (size_t)out_size * sizeof(float), stream);
        long long total_threads = (long long)n_edges * 16;
        int block = 256;
        int grid = (int)((total_threads + block - 1) / block);
        gcn_scatter_fallback<<<grid, block, 0, stream>>>(rows, cols, vals, embeds, out, n_edges);
        return;
    }

    u64* sorted = (u64*)d_ws;
    int* offg   = (int*)(sorted + n_edges);                  // [B+1][PB] transposed
    unsigned short* emb16 = (unsigned short*)
        (((uintptr_t)(offg + (size_t)(N_BUCKETS + 1) * PB) + 15) & ~(uintptr_t)15);

    bool use16 = (ws_size >= full_need);

    k_partition_conv<<<PB, K1_THREADS, 0, stream>>>(rows, cols, vals, sorted, offg,
                                                    embeds, emb16, use16 ? 1 : 0,
                                                    n_edges, n_elems, chunk);
    if (use16)
        k_aggregate_seg<true><<<N_BUCKETS, 512, 0, stream>>>(
            sorted, offg, embeds, emb16, out, n_nodes, chunk);
    else
        k_aggregate_seg<false><<<N_BUCKETS, 512, 0, stream>>>(
            sorted, offg, embeds, emb16, out, n_nodes, chunk);
}